// Round 1
// baseline (2126.385 us; speedup 1.0000x reference)
//
#include <hip/hip_runtime.h>

#define N_NODES 100000
#define IN_DIM 128
#define HID 128
#define N_REL 2
#define N_EDGES 500000

// ---------------------------------------------------------------------------
// Scatter: for each edge e, agg[rel][dst] += x[src]; cnt[rel][dst] += 1.
// 32 threads per edge, float4 per thread (128 floats/row).
// ---------------------------------------------------------------------------
__global__ __launch_bounds__(256) void scatter_kernel(
    const float* __restrict__ X,      // [N][128]
    const int* __restrict__ ei,       // [2][E] (src row, dst row)
    const int* __restrict__ et,       // [E]
    float* __restrict__ agg,          // [2][N][128]
    unsigned* __restrict__ cnt)       // [2][N]
{
    int t = blockIdx.x * blockDim.x + threadIdx.x;
    int e = t >> 5;
    int lane = t & 31;
    if (e >= N_EDGES) return;
    int src = ei[e];
    int dst = ei[N_EDGES + e];
    int r = et[e];
    const float4* x4 = (const float4*)(X + (size_t)src * IN_DIM);
    float4 v = x4[lane];
    float* dp = agg + ((size_t)r * N_NODES + dst) * HID + lane * 4;
    unsafeAtomicAdd(dp + 0, v.x);
    unsafeAtomicAdd(dp + 1, v.y);
    unsafeAtomicAdd(dp + 2, v.z);
    unsafeAtomicAdd(dp + 3, v.w);
    if (lane == 0) atomicAdd(cnt + (size_t)r * N_NODES + dst, 1u);
}

// ---------------------------------------------------------------------------
// minv[r][n] = 1 / max(cnt[r][n], 1)
// ---------------------------------------------------------------------------
__global__ void minv_kernel(const unsigned* __restrict__ cnt,
                            float* __restrict__ minv)
{
    int i = blockIdx.x * blockDim.x + threadIdx.x;
    if (i < N_REL * N_NODES) {
        unsigned c = cnt[i];
        minv[i] = 1.0f / (float)(c > 0u ? c : 1u);
    }
}

// ---------------------------------------------------------------------------
// Fused layer GEMM: out[n][c] = relu( b[c] + x[n]@Wroot + m0[n]@W0 + m1[n]@W1 )
// where m_r[n] = agg[r][n] * minv[r][n].  Treated as [32-node tile, K=384].
// FINAL: instead of storing H, computes logits = relu(H) @ Wc + bc -> Out.
// Block: 256 threads = 8 node-groups (tn) x 32 channel-groups (tc).
// Each thread: 4 nodes x 4 channels register tile.
// ---------------------------------------------------------------------------
template <bool FINAL>
__global__ __launch_bounds__(256) void gemm_kernel(
    const float* __restrict__ Xin,    // [N][128]
    const float* __restrict__ agg,    // [2][N][128]
    const float* __restrict__ minv,   // [2][N]
    const float* __restrict__ Wroot,  // [128][128] (k-major, c contiguous)
    const float* __restrict__ Wrel,   // [2][128][128]
    const float* __restrict__ bias,   // [128]
    float* __restrict__ Hout,         // [N][128]   (!FINAL)
    const float* __restrict__ Wc,     // [128][2]   (FINAL)
    const float* __restrict__ bc,     // [2]        (FINAL)
    float* __restrict__ Out)          // [N][2]     (FINAL)
{
    __shared__ float inT[32][36];   // [k][node], row stride 36 floats (144B, 16B-aligned)
    __shared__ float wT[32][128];   // [k][channel]

    const int t  = threadIdx.x;
    const int tc = t & 31;          // channel group: channels tc*4..tc*4+3
    const int tn = t >> 5;          // node group: nodes tn*4..tn*4+3
    const int n0 = blockIdx.x * 32;

    float acc[4][4];
    #pragma unroll
    for (int j = 0; j < 4; ++j) {
        float bj = bias[tc * 4 + j];
        #pragma unroll
        for (int i = 0; i < 4; ++i) acc[i][j] = bj;
    }

    for (int kc = 0; kc < 12; ++kc) {
        const int seg = kc >> 2;          // 0: root, 1: rel0, 2: rel1
        const int kl  = (kc & 3) * 32;    // k offset within segment
        const float* inp;
        const float* wp;
        if (seg == 0) { inp = Xin; wp = Wroot; }
        else {
            inp = agg + (size_t)(seg - 1) * N_NODES * HID;
            wp  = Wrel + (size_t)(seg - 1) * 128 * 128;
        }

        // stage input tile (32 nodes x 32 k), transposed into inT[k][n]
        {
            int n  = t >> 3;    // 0..31
            int kq = t & 7;     // 0..7 (float4 along k)
            int node = n0 + n;
            float4 v = *(const float4*)(inp + (size_t)node * 128 + kl + kq * 4);
            float s = 1.0f;
            if (seg > 0) s = minv[(size_t)(seg - 1) * N_NODES + node];
            inT[kq * 4 + 0][n] = v.x * s;
            inT[kq * 4 + 1][n] = v.y * s;
            inT[kq * 4 + 2][n] = v.z * s;
            inT[kq * 4 + 3][n] = v.w * s;
        }
        // stage weight tile (32 k x 128 c)
        #pragma unroll
        for (int i = 0; i < 4; ++i) {
            int idx = t + i * 256;        // 0..1023 float4 slots
            int row = idx >> 5;           // k 0..31
            int c4  = idx & 31;
            *(float4*)&wT[row][c4 * 4] =
                *(const float4*)(wp + (size_t)(kl + row) * 128 + c4 * 4);
        }
        __syncthreads();

        #pragma unroll
        for (int kk = 0; kk < 32; ++kk) {
            float4 a = *(float4*)&inT[kk][tn * 4];
            float4 w = *(float4*)&wT[kk][tc * 4];
            acc[0][0] += a.x * w.x; acc[0][1] += a.x * w.y; acc[0][2] += a.x * w.z; acc[0][3] += a.x * w.w;
            acc[1][0] += a.y * w.x; acc[1][1] += a.y * w.y; acc[1][2] += a.y * w.z; acc[1][3] += a.y * w.w;
            acc[2][0] += a.z * w.x; acc[2][1] += a.z * w.y; acc[2][2] += a.z * w.z; acc[2][3] += a.z * w.w;
            acc[3][0] += a.w * w.x; acc[3][1] += a.w * w.y; acc[3][2] += a.w * w.z; acc[3][3] += a.w * w.w;
        }
        __syncthreads();
    }

    if (!FINAL) {
        #pragma unroll
        for (int i = 0; i < 4; ++i) {
            int node = n0 + tn * 4 + i;
            float4 v;
            v.x = fmaxf(acc[i][0], 0.f);
            v.y = fmaxf(acc[i][1], 0.f);
            v.z = fmaxf(acc[i][2], 0.f);
            v.w = fmaxf(acc[i][3], 0.f);
            *(float4*)(Hout + (size_t)node * 128 + tc * 4) = v;
        }
    } else {
        // relu -> logits = h @ Wc + bc, reduce over channels (tc groups of 32 lanes)
        float p[4][2];
        #pragma unroll
        for (int i = 0; i < 4; ++i) { p[i][0] = 0.f; p[i][1] = 0.f; }
        #pragma unroll
        for (int j = 0; j < 4; ++j) {
            int c = tc * 4 + j;
            float w0 = Wc[c * 2 + 0];
            float w1 = Wc[c * 2 + 1];
            #pragma unroll
            for (int i = 0; i < 4; ++i) {
                float h = fmaxf(acc[i][j], 0.f);
                p[i][0] += h * w0;
                p[i][1] += h * w1;
            }
        }
        #pragma unroll
        for (int off = 16; off > 0; off >>= 1) {
            #pragma unroll
            for (int i = 0; i < 4; ++i) {
                p[i][0] += __shfl_down(p[i][0], off, 32);
                p[i][1] += __shfl_down(p[i][1], off, 32);
            }
        }
        if (tc == 0) {
            float b0 = bc[0], b1 = bc[1];
            #pragma unroll
            for (int i = 0; i < 4; ++i) {
                int node = n0 + tn * 4 + i;
                Out[(size_t)node * 2 + 0] = p[i][0] + b0;
                Out[(size_t)node * 2 + 1] = p[i][1] + b1;
            }
        }
    }
}

extern "C" void kernel_launch(void* const* d_in, const int* in_sizes, int n_in,
                              void* d_out, int out_size, void* d_ws, size_t ws_size,
                              hipStream_t stream)
{
    const float* x      = (const float*)d_in[0];
    const int*   ei     = (const int*)d_in[1];
    const int*   et     = (const int*)d_in[2];
    const float* Wrel1  = (const float*)d_in[3];
    const float* Wroot1 = (const float*)d_in[4];
    const float* b1     = (const float*)d_in[5];
    const float* Wrel2  = (const float*)d_in[6];
    const float* Wroot2 = (const float*)d_in[7];
    const float* b2     = (const float*)d_in[8];
    const float* Wc     = (const float*)d_in[9];
    const float* bc     = (const float*)d_in[10];
    float* out = (float*)d_out;

    char* ws = (char*)d_ws;
    const size_t aggsz  = (size_t)N_REL * N_NODES * HID * sizeof(float);
    const size_t cntsz  = (size_t)N_REL * N_NODES * sizeof(unsigned);
    const size_t minvsz = (size_t)N_REL * N_NODES * sizeof(float);
    float*    agg  = (float*)ws;
    unsigned* cnt  = (unsigned*)(ws + aggsz);
    float*    minv = (float*)(ws + aggsz + cntsz);
    float*    h1   = (float*)(ws + aggsz + cntsz + minvsz);

    const int scatter_blocks = (N_EDGES * 32 + 255) / 256;   // 62500
    const int minv_blocks    = (N_REL * N_NODES + 255) / 256;
    const int gemm_blocks    = N_NODES / 32;                  // 3125 (exact)

    // ---- layer 1 ----
    hipMemsetAsync(agg, 0, aggsz + cntsz, stream);
    scatter_kernel<<<scatter_blocks, 256, 0, stream>>>(x, ei, et, agg, cnt);
    minv_kernel<<<minv_blocks, 256, 0, stream>>>(cnt, minv);
    gemm_kernel<false><<<gemm_blocks, 256, 0, stream>>>(
        x, agg, minv, Wroot1, Wrel1, b1, h1, nullptr, nullptr, nullptr);

    // ---- layer 2 ----
    hipMemsetAsync(agg, 0, aggsz + cntsz, stream);
    scatter_kernel<<<scatter_blocks, 256, 0, stream>>>(h1, ei, et, agg, cnt);
    minv_kernel<<<minv_blocks, 256, 0, stream>>>(cnt, minv);
    gemm_kernel<true><<<gemm_blocks, 256, 0, stream>>>(
        h1, agg, minv, Wroot2, Wrel2, b2, nullptr, Wc, bc, out);
}

// Round 2
// 546.309 us; speedup vs baseline: 3.8923x; 3.8923x over previous
//
#include <hip/hip_runtime.h>

#define N_NODES 100000
#define IN_DIM 128
#define HID 128
#define N_REL 2
#define N_EDGES 500000
#define M_SEG (N_REL * N_NODES)          // 200000 (rel,node) segments
#define SCAN_BLK 1024                    // elements per scan block
#define SCAN_NB ((M_SEG + SCAN_BLK - 1) / SCAN_BLK)   // 196

// ---------------------------------------------------------------------------
// CSR build: histogram -> scan -> fill.  Graph is layer-invariant: build once.
// ---------------------------------------------------------------------------
__global__ __launch_bounds__(256) void hist_kernel(
    const int* __restrict__ ei, const int* __restrict__ et,
    unsigned* __restrict__ cnt)          // [M_SEG], pre-zeroed
{
    int e = blockIdx.x * blockDim.x + threadIdx.x;
    if (e >= N_EDGES) return;
    int dst = ei[N_EDGES + e];
    int r = et[e];
    atomicAdd(cnt + (size_t)r * N_NODES + dst, 1u);
}

// S1: per-block (1024 elems) exclusive prefix within block + block total
__global__ __launch_bounds__(256) void scan1_kernel(
    const unsigned* __restrict__ cnt,
    unsigned* __restrict__ rs,           // [M_SEG+1] block-local exclusive
    unsigned* __restrict__ bsums)        // [SCAN_NB]
{
    __shared__ unsigned sdata[256];
    int t = threadIdx.x;
    int base = blockIdx.x * SCAN_BLK + t * 4;
    unsigned v[4];
    unsigned s = 0;
    #pragma unroll
    for (int j = 0; j < 4; ++j) {
        v[j] = (base + j < M_SEG) ? cnt[base + j] : 0u;
        s += v[j];
    }
    sdata[t] = s;
    __syncthreads();
    #pragma unroll
    for (int off = 1; off < 256; off <<= 1) {
        unsigned x = (t >= off) ? sdata[t - off] : 0u;
        __syncthreads();
        if (t >= off) sdata[t] += x;
        __syncthreads();
    }
    unsigned excl = (t > 0) ? sdata[t - 1] : 0u;
    if (t == 255) bsums[blockIdx.x] = sdata[255];
    unsigned run = excl;
    #pragma unroll
    for (int j = 0; j < 4; ++j) {
        if (base + j < M_SEG) rs[base + j] = run;
        run += v[j];
    }
}

// S2: single block scans the block totals (exclusive, in place)
__global__ __launch_bounds__(256) void scan2_kernel(unsigned* __restrict__ bsums)
{
    __shared__ unsigned sdata[256];
    int t = threadIdx.x;
    sdata[t] = (t < SCAN_NB) ? bsums[t] : 0u;
    __syncthreads();
    #pragma unroll
    for (int off = 1; off < 256; off <<= 1) {
        unsigned x = (t >= off) ? sdata[t - off] : 0u;
        __syncthreads();
        if (t >= off) sdata[t] += x;
        __syncthreads();
    }
    if (t < SCAN_NB) bsums[t] = (t > 0) ? sdata[t - 1] : 0u;
}

// S3: add block offsets; init cursor = row start; write sentinel
__global__ __launch_bounds__(256) void scan3_kernel(
    unsigned* __restrict__ rs, const unsigned* __restrict__ bsums,
    unsigned* __restrict__ cursor)
{
    int i = blockIdx.x * blockDim.x + threadIdx.x;
    if (i < M_SEG) {
        unsigned v = rs[i] + bsums[i >> 10];
        rs[i] = v;
        cursor[i] = v;
    }
    if (i == 0) rs[M_SEG] = N_EDGES;
}

__global__ __launch_bounds__(256) void fill_kernel(
    const int* __restrict__ ei, const int* __restrict__ et,
    unsigned* __restrict__ cursor, unsigned* __restrict__ csr)
{
    int e = blockIdx.x * blockDim.x + threadIdx.x;
    if (e >= N_EDGES) return;
    int src = ei[e];
    int dst = ei[N_EDGES + e];
    int r = et[e];
    unsigned pos = atomicAdd(cursor + (size_t)r * N_NODES + dst, 1u);
    csr[pos] = (unsigned)src;
}

// ---------------------------------------------------------------------------
// Gather-aggregate: 32 lanes per (rel,node) segment; writes the MEAN row.
// ---------------------------------------------------------------------------
__global__ __launch_bounds__(256) void gather_kernel(
    const float* __restrict__ X,         // [N][128]
    const unsigned* __restrict__ rs,     // [M_SEG+1]
    const unsigned* __restrict__ csr,    // [E]
    float* __restrict__ agg)             // [2][N][128] (means)
{
    int t = blockIdx.x * blockDim.x + threadIdx.x;
    int seg = t >> 5;
    int lane = t & 31;
    if (seg >= M_SEG) return;
    unsigned start = rs[seg];
    unsigned end = rs[seg + 1];
    float4 acc = make_float4(0.f, 0.f, 0.f, 0.f);
    for (unsigned p = start; p < end; ++p) {
        unsigned s = csr[p];
        float4 v = ((const float4*)(X + (size_t)s * IN_DIM))[lane];
        acc.x += v.x; acc.y += v.y; acc.z += v.z; acc.w += v.w;
    }
    unsigned c = end - start;
    float scale = 1.0f / (float)(c > 0u ? c : 1u);
    acc.x *= scale; acc.y *= scale; acc.z *= scale; acc.w *= scale;
    ((float4*)(agg + (size_t)seg * HID))[lane] = acc;
}

// ---------------------------------------------------------------------------
// Fused layer GEMM: out[n][c] = relu( b[c] + x[n]@Wroot + m0[n]@W0 + m1[n]@W1 )
// agg already holds the per-relation means.  K = 384 over 3 segments.
// FINAL variant fuses relu(H) @ Wc + bc classifier head.
// ---------------------------------------------------------------------------
template <bool FINAL>
__global__ __launch_bounds__(256) void gemm_kernel(
    const float* __restrict__ Xin,    // [N][128]
    const float* __restrict__ agg,    // [2][N][128] (means)
    const float* __restrict__ Wroot,  // [128][128]
    const float* __restrict__ Wrel,   // [2][128][128]
    const float* __restrict__ bias,   // [128]
    float* __restrict__ Hout,         // [N][128]   (!FINAL)
    const float* __restrict__ Wc,     // [128][2]   (FINAL)
    const float* __restrict__ bc,     // [2]        (FINAL)
    float* __restrict__ Out)          // [N][2]     (FINAL)
{
    __shared__ float inT[32][36];
    __shared__ float wT[32][128];

    const int t  = threadIdx.x;
    const int tc = t & 31;
    const int tn = t >> 5;
    const int n0 = blockIdx.x * 32;

    float acc[4][4];
    #pragma unroll
    for (int j = 0; j < 4; ++j) {
        float bj = bias[tc * 4 + j];
        #pragma unroll
        for (int i = 0; i < 4; ++i) acc[i][j] = bj;
    }

    for (int kc = 0; kc < 12; ++kc) {
        const int seg = kc >> 2;
        const int kl  = (kc & 3) * 32;
        const float* inp;
        const float* wp;
        if (seg == 0) { inp = Xin; wp = Wroot; }
        else {
            inp = agg + (size_t)(seg - 1) * N_NODES * HID;
            wp  = Wrel + (size_t)(seg - 1) * 128 * 128;
        }

        {
            int n  = t >> 3;
            int kq = t & 7;
            int node = n0 + n;
            float4 v = *(const float4*)(inp + (size_t)node * 128 + kl + kq * 4);
            inT[kq * 4 + 0][n] = v.x;
            inT[kq * 4 + 1][n] = v.y;
            inT[kq * 4 + 2][n] = v.z;
            inT[kq * 4 + 3][n] = v.w;
        }
        #pragma unroll
        for (int i = 0; i < 4; ++i) {
            int idx = t + i * 256;
            int row = idx >> 5;
            int c4  = idx & 31;
            *(float4*)&wT[row][c4 * 4] =
                *(const float4*)(wp + (size_t)(kl + row) * 128 + c4 * 4);
        }
        __syncthreads();

        #pragma unroll
        for (int kk = 0; kk < 32; ++kk) {
            float4 a = *(float4*)&inT[kk][tn * 4];
            float4 w = *(float4*)&wT[kk][tc * 4];
            acc[0][0] += a.x * w.x; acc[0][1] += a.x * w.y; acc[0][2] += a.x * w.z; acc[0][3] += a.x * w.w;
            acc[1][0] += a.y * w.x; acc[1][1] += a.y * w.y; acc[1][2] += a.y * w.z; acc[1][3] += a.y * w.w;
            acc[2][0] += a.z * w.x; acc[2][1] += a.z * w.y; acc[2][2] += a.z * w.z; acc[2][3] += a.z * w.w;
            acc[3][0] += a.w * w.x; acc[3][1] += a.w * w.y; acc[3][2] += a.w * w.z; acc[3][3] += a.w * w.w;
        }
        __syncthreads();
    }

    if (!FINAL) {
        #pragma unroll
        for (int i = 0; i < 4; ++i) {
            int node = n0 + tn * 4 + i;
            float4 v;
            v.x = fmaxf(acc[i][0], 0.f);
            v.y = fmaxf(acc[i][1], 0.f);
            v.z = fmaxf(acc[i][2], 0.f);
            v.w = fmaxf(acc[i][3], 0.f);
            *(float4*)(Hout + (size_t)node * 128 + tc * 4) = v;
        }
    } else {
        float p[4][2];
        #pragma unroll
        for (int i = 0; i < 4; ++i) { p[i][0] = 0.f; p[i][1] = 0.f; }
        #pragma unroll
        for (int j = 0; j < 4; ++j) {
            int c = tc * 4 + j;
            float w0 = Wc[c * 2 + 0];
            float w1 = Wc[c * 2 + 1];
            #pragma unroll
            for (int i = 0; i < 4; ++i) {
                float h = fmaxf(acc[i][j], 0.f);
                p[i][0] += h * w0;
                p[i][1] += h * w1;
            }
        }
        #pragma unroll
        for (int off = 16; off > 0; off >>= 1) {
            #pragma unroll
            for (int i = 0; i < 4; ++i) {
                p[i][0] += __shfl_down(p[i][0], off, 32);
                p[i][1] += __shfl_down(p[i][1], off, 32);
            }
        }
        if (tc == 0) {
            float b0 = bc[0], b1 = bc[1];
            #pragma unroll
            for (int i = 0; i < 4; ++i) {
                int node = n0 + tn * 4 + i;
                Out[(size_t)node * 2 + 0] = p[i][0] + b0;
                Out[(size_t)node * 2 + 1] = p[i][1] + b1;
            }
        }
    }
}

extern "C" void kernel_launch(void* const* d_in, const int* in_sizes, int n_in,
                              void* d_out, int out_size, void* d_ws, size_t ws_size,
                              hipStream_t stream)
{
    const float* x      = (const float*)d_in[0];
    const int*   ei     = (const int*)d_in[1];
    const int*   et     = (const int*)d_in[2];
    const float* Wrel1  = (const float*)d_in[3];
    const float* Wroot1 = (const float*)d_in[4];
    const float* b1     = (const float*)d_in[5];
    const float* Wrel2  = (const float*)d_in[6];
    const float* Wroot2 = (const float*)d_in[7];
    const float* b2     = (const float*)d_in[8];
    const float* Wc     = (const float*)d_in[9];
    const float* bc     = (const float*)d_in[10];
    float* out = (float*)d_out;

    char* ws = (char*)d_ws;
    size_t off = 0;
    auto alloc = [&](size_t bytes) {
        void* p = ws + off;
        off += (bytes + 15) & ~(size_t)15;
        return p;
    };
    float*    agg    = (float*)alloc((size_t)N_REL * N_NODES * HID * sizeof(float));
    float*    h1     = (float*)alloc((size_t)N_NODES * HID * sizeof(float));
    unsigned* rs     = (unsigned*)alloc((size_t)(M_SEG + 1) * sizeof(unsigned));
    unsigned* cursor = (unsigned*)alloc((size_t)M_SEG * sizeof(unsigned));   // also histogram counts
    unsigned* bsums  = (unsigned*)alloc(256 * sizeof(unsigned));
    unsigned* csr    = (unsigned*)alloc((size_t)N_EDGES * sizeof(unsigned));

    const int edge_blocks   = (N_EDGES + 255) / 256;
    const int seg_blocks    = (M_SEG + 255) / 256;
    const int gather_blocks = (M_SEG * 32 + 255) / 256;       // 25000
    const int gemm_blocks   = N_NODES / 32;                   // 3125

    // ---- CSR build (graph identical for both layers) ----
    hipMemsetAsync(cursor, 0, (size_t)M_SEG * sizeof(unsigned), stream);
    hist_kernel<<<edge_blocks, 256, 0, stream>>>(ei, et, cursor);
    scan1_kernel<<<SCAN_NB, 256, 0, stream>>>(cursor, rs, bsums);
    scan2_kernel<<<1, 256, 0, stream>>>(bsums);
    scan3_kernel<<<seg_blocks, 256, 0, stream>>>(rs, bsums, cursor);
    fill_kernel<<<edge_blocks, 256, 0, stream>>>(ei, et, cursor, csr);

    // ---- layer 1 ----
    gather_kernel<<<gather_blocks, 256, 0, stream>>>(x, rs, csr, agg);
    gemm_kernel<false><<<gemm_blocks, 256, 0, stream>>>(
        x, agg, Wroot1, Wrel1, b1, h1, nullptr, nullptr, nullptr);

    // ---- layer 2 ----
    gather_kernel<<<gather_blocks, 256, 0, stream>>>(h1, rs, csr, agg);
    gemm_kernel<true><<<gemm_blocks, 256, 0, stream>>>(
        h1, agg, Wroot2, Wrel2, b2, nullptr, Wc, bc, out);
}

// Round 3
// 348.289 us; speedup vs baseline: 6.1052x; 1.5686x over previous
//
#include <hip/hip_runtime.h>

#define N_NODES 100000
#define PAD_N   100096                   // 782 * 128, padded M for GEMM tiles
#define IN_DIM 128
#define HID 128
#define N_REL 2
#define N_EDGES 500000
#define M_SEG (N_REL * N_NODES)          // 200000 (rel,node) segments
#define SCAN_BLK 1024
#define SCAN_NB ((M_SEG + SCAN_BLK - 1) / SCAN_BLK)   // 196

typedef __attribute__((ext_vector_type(8))) short short8;
typedef __attribute__((ext_vector_type(4))) float float4v;

__device__ __forceinline__ unsigned short f2b(float f) {
    unsigned u = __float_as_uint(f);
    u += 0x7FFFu + ((u >> 16) & 1u);     // round-to-nearest-even
    return (unsigned short)(u >> 16);
}
__device__ __forceinline__ float b2f(unsigned short b) {
    return __uint_as_float(((unsigned)b) << 16);
}

// ---------------------------------------------------------------------------
// CSR build: histogram -> scan -> fill.  Graph is layer-invariant: build once.
// ---------------------------------------------------------------------------
__global__ __launch_bounds__(256) void hist_kernel(
    const int* __restrict__ ei, const int* __restrict__ et,
    unsigned* __restrict__ cnt)
{
    int e = blockIdx.x * blockDim.x + threadIdx.x;
    if (e >= N_EDGES) return;
    int dst = ei[N_EDGES + e];
    int r = et[e];
    atomicAdd(cnt + (size_t)r * N_NODES + dst, 1u);
}

__global__ __launch_bounds__(256) void scan1_kernel(
    const unsigned* __restrict__ cnt,
    unsigned* __restrict__ rs, unsigned* __restrict__ bsums)
{
    __shared__ unsigned sdata[256];
    int t = threadIdx.x;
    int base = blockIdx.x * SCAN_BLK + t * 4;
    unsigned v[4]; unsigned s = 0;
    #pragma unroll
    for (int j = 0; j < 4; ++j) {
        v[j] = (base + j < M_SEG) ? cnt[base + j] : 0u;
        s += v[j];
    }
    sdata[t] = s;
    __syncthreads();
    #pragma unroll
    for (int off = 1; off < 256; off <<= 1) {
        unsigned x = (t >= off) ? sdata[t - off] : 0u;
        __syncthreads();
        if (t >= off) sdata[t] += x;
        __syncthreads();
    }
    unsigned excl = (t > 0) ? sdata[t - 1] : 0u;
    if (t == 255) bsums[blockIdx.x] = sdata[255];
    unsigned run = excl;
    #pragma unroll
    for (int j = 0; j < 4; ++j) {
        if (base + j < M_SEG) rs[base + j] = run;
        run += v[j];
    }
}

__global__ __launch_bounds__(256) void scan2_kernel(unsigned* __restrict__ bsums)
{
    __shared__ unsigned sdata[256];
    int t = threadIdx.x;
    sdata[t] = (t < SCAN_NB) ? bsums[t] : 0u;
    __syncthreads();
    #pragma unroll
    for (int off = 1; off < 256; off <<= 1) {
        unsigned x = (t >= off) ? sdata[t - off] : 0u;
        __syncthreads();
        if (t >= off) sdata[t] += x;
        __syncthreads();
    }
    if (t < SCAN_NB) bsums[t] = (t > 0) ? sdata[t - 1] : 0u;
}

__global__ __launch_bounds__(256) void scan3_kernel(
    unsigned* __restrict__ rs, const unsigned* __restrict__ bsums,
    unsigned* __restrict__ cursor)
{
    int i = blockIdx.x * blockDim.x + threadIdx.x;
    if (i < M_SEG) {
        unsigned v = rs[i] + bsums[i >> 10];
        rs[i] = v;
        cursor[i] = v;
    }
    if (i == 0) rs[M_SEG] = N_EDGES;
}

__global__ __launch_bounds__(256) void fill_kernel(
    const int* __restrict__ ei, const int* __restrict__ et,
    unsigned* __restrict__ cursor, unsigned* __restrict__ csr)
{
    int e = blockIdx.x * blockDim.x + threadIdx.x;
    if (e >= N_EDGES) return;
    int src = ei[e];
    int dst = ei[N_EDGES + e];
    int r = et[e];
    unsigned pos = atomicAdd(cursor + (size_t)r * N_NODES + dst, 1u);
    csr[pos] = (unsigned)src;
}

// ---------------------------------------------------------------------------
// Convert fp32 x -> bf16 rows
// ---------------------------------------------------------------------------
__global__ __launch_bounds__(256) void cvt_kernel(
    const float* __restrict__ X, unsigned short* __restrict__ Xb)
{
    int i = blockIdx.x * blockDim.x + threadIdx.x;   // float4 index
    if (i >= N_NODES * IN_DIM / 4) return;
    float4 v = ((const float4*)X)[i];
    ushort4 o;
    o.x = f2b(v.x); o.y = f2b(v.y); o.z = f2b(v.z); o.w = f2b(v.w);
    ((ushort4*)Xb)[i] = o;
}

// ---------------------------------------------------------------------------
// Pack weights into B-fragment order for mfma_f32_16x16x32_bf16.
// Wp[layer][kstep 0..11][ntile 0..7][lane 0..63][j 0..7] =
//   W_seg[(kstep%4)*32 + (lane>>4)*8 + j][ntile*16 + (lane&15)],  seg = kstep/4
// ---------------------------------------------------------------------------
__global__ __launch_bounds__(256) void pack_kernel(
    const float* __restrict__ Wroot1, const float* __restrict__ Wrel1,
    const float* __restrict__ Wroot2, const float* __restrict__ Wrel2,
    unsigned short* __restrict__ Wp)
{
    int tid = blockIdx.x * blockDim.x + threadIdx.x;
    if (tid >= 2 * 12 * 8 * 64) return;
    int layer = tid / 6144;
    int rem   = tid % 6144;
    int ks    = rem / 512;
    int rem2  = rem % 512;
    int nt    = rem2 / 64;
    int lane  = rem2 % 64;
    int seg = ks >> 2;
    int kl  = (ks & 3) * 32 + (lane >> 4) * 8;
    int chan = nt * 16 + (lane & 15);
    const float* Wroot = layer ? Wroot2 : Wroot1;
    const float* Wrel  = layer ? Wrel2  : Wrel1;
    const float* W = (seg == 0) ? Wroot : (Wrel + (size_t)(seg - 1) * 128 * 128);
    unsigned short* dst = Wp + (size_t)tid * 8;
    #pragma unroll
    for (int j = 0; j < 8; ++j)
        dst[j] = f2b(W[(size_t)(kl + j) * 128 + chan]);
}

// ---------------------------------------------------------------------------
// Gather-aggregate (bf16): 32 lanes per (rel,node) segment; writes MEAN row.
// ---------------------------------------------------------------------------
__global__ __launch_bounds__(256) void gather_kernel(
    const unsigned short* __restrict__ Xb,   // [PAD_N][128] bf16
    const unsigned* __restrict__ rs,
    const unsigned* __restrict__ csr,
    unsigned short* __restrict__ agg)        // [2][PAD_N][128] bf16 means
{
    int t = blockIdx.x * blockDim.x + threadIdx.x;
    int seg = t >> 5;
    int lane = t & 31;
    if (seg >= M_SEG) return;
    unsigned start = rs[seg];
    unsigned end = rs[seg + 1];
    float a0 = 0.f, a1 = 0.f, a2 = 0.f, a3 = 0.f;
    for (unsigned p = start; p < end; ++p) {
        unsigned s = csr[p];
        uint2 v = ((const uint2*)(Xb + (size_t)s * IN_DIM))[lane];
        a0 += __uint_as_float(v.x << 16);
        a1 += __uint_as_float(v.x & 0xFFFF0000u);
        a2 += __uint_as_float(v.y << 16);
        a3 += __uint_as_float(v.y & 0xFFFF0000u);
    }
    unsigned c = end - start;
    float scale = 1.0f / (float)(c > 0u ? c : 1u);
    a0 *= scale; a1 *= scale; a2 *= scale; a3 *= scale;
    int r = seg / N_NODES;
    int n = seg % N_NODES;
    uint2 o;
    o.x = ((unsigned)f2b(a1) << 16) | (unsigned)f2b(a0);
    o.y = ((unsigned)f2b(a3) << 16) | (unsigned)f2b(a2);
    ((uint2*)(agg + ((size_t)r * PAD_N + n) * HID))[lane] = o;
}

// ---------------------------------------------------------------------------
// MFMA GEMM: Out[n][c] = relu(b[c] + x[n]@Wroot + m0[n]@W0 + m1[n]@W1)
// K=384 (3 segs x 128). Block = 128 nodes = 4 waves x (2 Mtiles x 8 Ntiles).
// A-frags: direct 16B global loads from bf16 rows.  B-frags: packed Wp.
// FINAL fuses the relu(H) @ Wc + bc classifier head.
// ---------------------------------------------------------------------------
template <bool FINAL>
__global__ __launch_bounds__(256) void gemm_kernel(
    const unsigned short* __restrict__ Xin,   // [PAD_N][128] bf16
    const unsigned short* __restrict__ agg,   // [2][PAD_N][128] bf16
    const unsigned short* __restrict__ Wp,    // packed [12][8][64][8] bf16
    const float* __restrict__ bias,           // [128] fp32
    unsigned short* __restrict__ Hout,        // [PAD_N][128] bf16 (!FINAL)
    const float* __restrict__ Wc,             // [128][2] fp32 (FINAL)
    const float* __restrict__ bc,             // [2] fp32 (FINAL)
    float* __restrict__ Out)                  // [N][2] fp32 (FINAL)
{
    const int t    = threadIdx.x;
    const int w    = t >> 6;          // wave 0..3
    const int lane = t & 63;
    const int l15  = lane & 15;
    const int quad = lane >> 4;
    const int rowbase = blockIdx.x * 128 + w * 32;   // this wave's 32 nodes

    float4v acc[2][8];
    #pragma unroll
    for (int nt = 0; nt < 8; ++nt) {
        float bv = bias[nt * 16 + l15];
        #pragma unroll
        for (int mt = 0; mt < 2; ++mt)
            acc[mt][nt] = float4v{bv, bv, bv, bv};
    }

    #pragma unroll
    for (int ks = 0; ks < 12; ++ks) {
        const int seg = ks >> 2;
        const int kcol = (ks & 3) * 32 + quad * 8;
        const unsigned short* abase =
            (seg == 0) ? Xin : (agg + (size_t)(seg - 1) * PAD_N * HID);
        short8 a0 = *(const short8*)(abase + (size_t)(rowbase + l15) * 128 + kcol);
        short8 a1 = *(const short8*)(abase + (size_t)(rowbase + 16 + l15) * 128 + kcol);
        const unsigned short* bbase = Wp + ((size_t)ks * 8 * 64 + lane) * 8;
        #pragma unroll
        for (int nt = 0; nt < 8; ++nt) {
            short8 b = *(const short8*)(bbase + (size_t)nt * 64 * 8);
            acc[0][nt] = __builtin_amdgcn_mfma_f32_16x16x32_bf16(a0, b, acc[0][nt], 0, 0, 0);
            acc[1][nt] = __builtin_amdgcn_mfma_f32_16x16x32_bf16(a1, b, acc[1][nt], 0, 0, 0);
        }
    }

    if (!FINAL) {
        // D layout: row = quad*4 + r, col = l15 (within each 16x16 tile)
        #pragma unroll
        for (int mt = 0; mt < 2; ++mt) {
            #pragma unroll
            for (int r = 0; r < 4; ++r) {
                int node = rowbase + mt * 16 + quad * 4 + r;
                unsigned short* hp = Hout + (size_t)node * 128 + l15;
                #pragma unroll
                for (int nt = 0; nt < 8; ++nt)
                    hp[nt * 16] = f2b(fmaxf(acc[mt][nt][r], 0.f));
            }
        }
    } else {
        float wc0[8], wc1[8];
        #pragma unroll
        for (int nt = 0; nt < 8; ++nt) {
            wc0[nt] = Wc[(nt * 16 + l15) * 2 + 0];
            wc1[nt] = Wc[(nt * 16 + l15) * 2 + 1];
        }
        float b0 = bc[0], b1 = bc[1];
        #pragma unroll
        for (int mt = 0; mt < 2; ++mt) {
            #pragma unroll
            for (int r = 0; r < 4; ++r) {
                float l0 = 0.f, l1 = 0.f;
                #pragma unroll
                for (int nt = 0; nt < 8; ++nt) {
                    float h = fmaxf(acc[mt][nt][r], 0.f);
                    l0 += h * wc0[nt];
                    l1 += h * wc1[nt];
                }
                #pragma unroll
                for (int off = 8; off > 0; off >>= 1) {
                    l0 += __shfl_down(l0, off, 16);
                    l1 += __shfl_down(l1, off, 16);
                }
                int node = rowbase + mt * 16 + quad * 4 + r;
                if (l15 == 0 && node < N_NODES) {
                    Out[(size_t)node * 2 + 0] = l0 + b0;
                    Out[(size_t)node * 2 + 1] = l1 + b1;
                }
            }
        }
    }
}

extern "C" void kernel_launch(void* const* d_in, const int* in_sizes, int n_in,
                              void* d_out, int out_size, void* d_ws, size_t ws_size,
                              hipStream_t stream)
{
    const float* x      = (const float*)d_in[0];
    const int*   ei     = (const int*)d_in[1];
    const int*   et     = (const int*)d_in[2];
    const float* Wrel1  = (const float*)d_in[3];
    const float* Wroot1 = (const float*)d_in[4];
    const float* b1     = (const float*)d_in[5];
    const float* Wrel2  = (const float*)d_in[6];
    const float* Wroot2 = (const float*)d_in[7];
    const float* b2     = (const float*)d_in[8];
    const float* Wc     = (const float*)d_in[9];
    const float* bc     = (const float*)d_in[10];
    float* out = (float*)d_out;

    char* ws = (char*)d_ws;
    size_t off = 0;
    auto alloc = [&](size_t bytes) {
        void* p = ws + off;
        off += (bytes + 255) & ~(size_t)255;
        return p;
    };
    unsigned short* aggb  = (unsigned short*)alloc((size_t)N_REL * PAD_N * HID * 2);
    unsigned short* xb    = (unsigned short*)alloc((size_t)PAD_N * IN_DIM * 2);
    unsigned short* h1b   = (unsigned short*)alloc((size_t)PAD_N * HID * 2);
    unsigned short* Wp    = (unsigned short*)alloc((size_t)2 * 12 * 8 * 64 * 8 * 2);
    unsigned*       rs    = (unsigned*)alloc((size_t)(M_SEG + 1) * 4);
    unsigned*       cursor= (unsigned*)alloc((size_t)M_SEG * 4);
    unsigned*       bsums = (unsigned*)alloc(256 * 4);
    unsigned*       csr   = (unsigned*)alloc((size_t)N_EDGES * 4);

    const int edge_blocks   = (N_EDGES + 255) / 256;
    const int seg_blocks    = (M_SEG + 255) / 256;
    const int gather_blocks = (M_SEG * 32 + 255) / 256;   // 25000
    const int gemm_blocks   = PAD_N / 128;                // 782
    const int cvt_blocks    = (N_NODES * IN_DIM / 4 + 255) / 256;

    // ---- CSR build + conversions (graph identical for both layers) ----
    hipMemsetAsync(cursor, 0, (size_t)M_SEG * 4, stream);
    hist_kernel<<<edge_blocks, 256, 0, stream>>>(ei, et, cursor);
    scan1_kernel<<<SCAN_NB, 256, 0, stream>>>(cursor, rs, bsums);
    scan2_kernel<<<1, 256, 0, stream>>>(bsums);
    scan3_kernel<<<seg_blocks, 256, 0, stream>>>(rs, bsums, cursor);
    fill_kernel<<<edge_blocks, 256, 0, stream>>>(ei, et, cursor, csr);
    cvt_kernel<<<cvt_blocks, 256, 0, stream>>>(x, xb);
    pack_kernel<<<48, 256, 0, stream>>>(Wroot1, Wrel1, Wroot2, Wrel2, Wp);

    // ---- layer 1 ----
    gather_kernel<<<gather_blocks, 256, 0, stream>>>(xb, rs, csr, aggb);
    gemm_kernel<false><<<gemm_blocks, 256, 0, stream>>>(
        xb, aggb, Wp, b1, h1b, nullptr, nullptr, nullptr);

    // ---- layer 2 ----
    gather_kernel<<<gather_blocks, 256, 0, stream>>>(h1b, rs, csr, aggb);
    gemm_kernel<true><<<gemm_blocks, 256, 0, stream>>>(
        h1b, aggb, Wp + (size_t)12 * 8 * 64 * 8, b2, nullptr, Wc, bc, out);
}

// Round 4
// 302.619 us; speedup vs baseline: 7.0266x; 1.1509x over previous
//
#include <hip/hip_runtime.h>

#define N_NODES 100000
#define PAD_N   100096                   // 782 * 128, padded M for GEMM tiles
#define IN_DIM 128
#define HID 128
#define N_REL 2
#define N_EDGES 500000
#define M_SEG (N_REL * N_NODES)          // 200000 (rel,node) segments
#define SCAN_BLK 1024
#define SCAN_NB ((M_SEG + SCAN_BLK - 1) / SCAN_BLK)   // 196

typedef __attribute__((ext_vector_type(8))) short short8;
typedef __attribute__((ext_vector_type(4))) float float4v;

__device__ __forceinline__ unsigned short f2b(float f) {
    unsigned u = __float_as_uint(f);
    u += 0x7FFFu + ((u >> 16) & 1u);     // round-to-nearest-even
    return (unsigned short)(u >> 16);
}

// ---------------------------------------------------------------------------
// CSR build: histogram -> scan -> fill.  Graph is layer-invariant: build once.
// ---------------------------------------------------------------------------
__global__ __launch_bounds__(256) void hist_kernel(
    const int* __restrict__ ei, const int* __restrict__ et,
    unsigned* __restrict__ cnt)
{
    int e = blockIdx.x * blockDim.x + threadIdx.x;
    if (e >= N_EDGES) return;
    int dst = ei[N_EDGES + e];
    int r = et[e];
    atomicAdd(cnt + (size_t)r * N_NODES + dst, 1u);
}

__global__ __launch_bounds__(256) void scan1_kernel(
    const unsigned* __restrict__ cnt,
    unsigned* __restrict__ rs, unsigned* __restrict__ bsums)
{
    __shared__ unsigned sdata[256];
    int t = threadIdx.x;
    int base = blockIdx.x * SCAN_BLK + t * 4;
    unsigned v[4]; unsigned s = 0;
    #pragma unroll
    for (int j = 0; j < 4; ++j) {
        v[j] = (base + j < M_SEG) ? cnt[base + j] : 0u;
        s += v[j];
    }
    sdata[t] = s;
    __syncthreads();
    #pragma unroll
    for (int off = 1; off < 256; off <<= 1) {
        unsigned x = (t >= off) ? sdata[t - off] : 0u;
        __syncthreads();
        if (t >= off) sdata[t] += x;
        __syncthreads();
    }
    unsigned excl = (t > 0) ? sdata[t - 1] : 0u;
    if (t == 255) bsums[blockIdx.x] = sdata[255];
    unsigned run = excl;
    #pragma unroll
    for (int j = 0; j < 4; ++j) {
        if (base + j < M_SEG) rs[base + j] = run;
        run += v[j];
    }
}

__global__ __launch_bounds__(256) void scan2_kernel(unsigned* __restrict__ bsums)
{
    __shared__ unsigned sdata[256];
    int t = threadIdx.x;
    sdata[t] = (t < SCAN_NB) ? bsums[t] : 0u;
    __syncthreads();
    #pragma unroll
    for (int off = 1; off < 256; off <<= 1) {
        unsigned x = (t >= off) ? sdata[t - off] : 0u;
        __syncthreads();
        if (t >= off) sdata[t] += x;
        __syncthreads();
    }
    if (t < SCAN_NB) bsums[t] = (t > 0) ? sdata[t - 1] : 0u;
}

__global__ __launch_bounds__(256) void scan3_kernel(
    unsigned* __restrict__ rs, const unsigned* __restrict__ bsums,
    unsigned* __restrict__ cursor)
{
    int i = blockIdx.x * blockDim.x + threadIdx.x;
    if (i < M_SEG) {
        unsigned v = rs[i] + bsums[i >> 10];
        rs[i] = v;
        cursor[i] = v;
    }
    if (i == 0) rs[M_SEG] = N_EDGES;
}

__global__ __launch_bounds__(256) void fill_kernel(
    const int* __restrict__ ei, const int* __restrict__ et,
    unsigned* __restrict__ cursor, unsigned* __restrict__ csr)
{
    int e = blockIdx.x * blockDim.x + threadIdx.x;
    if (e >= N_EDGES) return;
    int src = ei[e];
    int dst = ei[N_EDGES + e];
    int r = et[e];
    unsigned pos = atomicAdd(cursor + (size_t)r * N_NODES + dst, 1u);
    csr[pos] = (unsigned)src;
}

// ---------------------------------------------------------------------------
// Convert fp32 x -> bf16 rows
// ---------------------------------------------------------------------------
__global__ __launch_bounds__(256) void cvt_kernel(
    const float* __restrict__ X, unsigned short* __restrict__ Xb)
{
    int i = blockIdx.x * blockDim.x + threadIdx.x;   // float4 index
    if (i >= N_NODES * IN_DIM / 4) return;
    float4 v = ((const float4*)X)[i];
    ushort4 o;
    o.x = f2b(v.x); o.y = f2b(v.y); o.z = f2b(v.z); o.w = f2b(v.w);
    ((ushort4*)Xb)[i] = o;
}

// ---------------------------------------------------------------------------
// Pack weights into B-fragment order for mfma_f32_16x16x32_bf16.
// Wp[layer][kstep 0..11][ntile 0..7][lane 0..63][j 0..7] =
//   W_seg[(kstep%4)*32 + (lane>>4)*8 + j][ntile*16 + (lane&15)],  seg = kstep/4
// ---------------------------------------------------------------------------
__global__ __launch_bounds__(256) void pack_kernel(
    const float* __restrict__ Wroot1, const float* __restrict__ Wrel1,
    const float* __restrict__ Wroot2, const float* __restrict__ Wrel2,
    unsigned short* __restrict__ Wp)
{
    int tid = blockIdx.x * blockDim.x + threadIdx.x;
    if (tid >= 2 * 12 * 8 * 64) return;
    int layer = tid / 6144;
    int rem   = tid % 6144;
    int ks    = rem / 512;
    int rem2  = rem % 512;
    int nt    = rem2 / 64;
    int lane  = rem2 % 64;
    int seg = ks >> 2;
    int kl  = (ks & 3) * 32 + (lane >> 4) * 8;
    int chan = nt * 16 + (lane & 15);
    const float* Wroot = layer ? Wroot2 : Wroot1;
    const float* Wrel  = layer ? Wrel2  : Wrel1;
    const float* W = (seg == 0) ? Wroot : (Wrel + (size_t)(seg - 1) * 128 * 128);
    unsigned short* dst = Wp + (size_t)tid * 8;
    #pragma unroll
    for (int j = 0; j < 8; ++j)
        dst[j] = f2b(W[(size_t)(kl + j) * 128 + chan]);
}

// ---------------------------------------------------------------------------
// Gather-aggregate (bf16): 32 lanes per (rel,node) segment; writes MEAN row.
// Unrolled by 2 with independent accumulators to keep 2 row-loads in flight.
// ---------------------------------------------------------------------------
__global__ __launch_bounds__(256) void gather_kernel(
    const unsigned short* __restrict__ Xb,   // [PAD_N][128] bf16
    const unsigned* __restrict__ rs,
    const unsigned* __restrict__ csr,
    unsigned short* __restrict__ agg)        // [2][PAD_N][128] bf16 means
{
    int t = blockIdx.x * blockDim.x + threadIdx.x;
    int seg = t >> 5;
    int lane = t & 31;
    if (seg >= M_SEG) return;
    unsigned start = rs[seg];
    unsigned end = rs[seg + 1];
    float a0 = 0.f, a1 = 0.f, a2 = 0.f, a3 = 0.f;
    float c0 = 0.f, c1 = 0.f, c2 = 0.f, c3 = 0.f;
    unsigned p = start;
    for (; p + 2 <= end; p += 2) {
        unsigned s0 = csr[p];
        unsigned s1 = csr[p + 1];
        uint2 v0 = ((const uint2*)(Xb + (size_t)s0 * IN_DIM))[lane];
        uint2 v1 = ((const uint2*)(Xb + (size_t)s1 * IN_DIM))[lane];
        a0 += __uint_as_float(v0.x << 16);
        a1 += __uint_as_float(v0.x & 0xFFFF0000u);
        a2 += __uint_as_float(v0.y << 16);
        a3 += __uint_as_float(v0.y & 0xFFFF0000u);
        c0 += __uint_as_float(v1.x << 16);
        c1 += __uint_as_float(v1.x & 0xFFFF0000u);
        c2 += __uint_as_float(v1.y << 16);
        c3 += __uint_as_float(v1.y & 0xFFFF0000u);
    }
    if (p < end) {
        unsigned s0 = csr[p];
        uint2 v0 = ((const uint2*)(Xb + (size_t)s0 * IN_DIM))[lane];
        a0 += __uint_as_float(v0.x << 16);
        a1 += __uint_as_float(v0.x & 0xFFFF0000u);
        a2 += __uint_as_float(v0.y << 16);
        a3 += __uint_as_float(v0.y & 0xFFFF0000u);
    }
    a0 += c0; a1 += c1; a2 += c2; a3 += c3;
    unsigned c = end - start;
    float scale = 1.0f / (float)(c > 0u ? c : 1u);
    a0 *= scale; a1 *= scale; a2 *= scale; a3 *= scale;
    int r = seg / N_NODES;
    int n = seg % N_NODES;
    uint2 o;
    o.x = ((unsigned)f2b(a1) << 16) | (unsigned)f2b(a0);
    o.y = ((unsigned)f2b(a3) << 16) | (unsigned)f2b(a2);
    ((uint2*)(agg + ((size_t)r * PAD_N + n) * HID))[lane] = o;
}

// ---------------------------------------------------------------------------
// MFMA GEMM: Out[n][c] = relu(b[c] + x[n]@Wroot + m0[n]@W0 + m1[n]@W1)
// K=384 (3 segs x 128). Block = 128 nodes = 4 waves x (2 Mtiles x 8 Ntiles).
// Explicit register staging: all 8 B-frags loaded before the MFMA burst;
// next K-step's A-frags prefetched during the current burst.
// ---------------------------------------------------------------------------
template <bool FINAL>
__global__ __launch_bounds__(256) void gemm_kernel(
    const unsigned short* __restrict__ Xin,   // [PAD_N][128] bf16
    const unsigned short* __restrict__ agg,   // [2][PAD_N][128] bf16
    const unsigned short* __restrict__ Wp,    // packed [12][8][64][8] bf16
    const float* __restrict__ bias,           // [128] fp32
    unsigned short* __restrict__ Hout,        // [PAD_N][128] bf16 (!FINAL)
    const float* __restrict__ Wc,             // [128][2] fp32 (FINAL)
    const float* __restrict__ bc,             // [2] fp32 (FINAL)
    float* __restrict__ Out)                  // [N][2] fp32 (FINAL)
{
    const int t    = threadIdx.x;
    const int w    = t >> 6;          // wave 0..3
    const int lane = t & 63;
    const int l15  = lane & 15;
    const int quad = lane >> 4;
    const int rowbase = blockIdx.x * 128 + w * 32;   // this wave's 32 nodes
    const int koff = quad * 8;

    float4v acc[2][8];
    #pragma unroll
    for (int nt = 0; nt < 8; ++nt) {
        float bv = bias[nt * 16 + l15];
        #pragma unroll
        for (int mt = 0; mt < 2; ++mt)
            acc[mt][nt] = float4v{bv, bv, bv, bv};
    }

    // A-frag address for K-step ks, M-tile mt
    auto aaddr = [&](int ks, int mt) -> const short8* {
        int seg = ks >> 2;
        int kcol = (ks & 3) * 32 + koff;
        const unsigned short* abase =
            (seg == 0) ? Xin : (agg + (size_t)(seg - 1) * PAD_N * HID);
        return (const short8*)(abase + (size_t)(rowbase + mt * 16 + l15) * 128 + kcol);
    };

    short8 a0 = *aaddr(0, 0);
    short8 a1 = *aaddr(0, 1);

    #pragma unroll
    for (int ks = 0; ks < 12; ++ks) {
        const unsigned short* bbase = Wp + ((size_t)ks * 8 * 64 + lane) * 8;
        short8 b[8];
        #pragma unroll
        for (int nt = 0; nt < 8; ++nt)
            b[nt] = *(const short8*)(bbase + (size_t)nt * 64 * 8);
        short8 na0, na1;
        if (ks < 11) {
            na0 = *aaddr(ks + 1, 0);
            na1 = *aaddr(ks + 1, 1);
        }
        #pragma unroll
        for (int nt = 0; nt < 8; ++nt) {
            acc[0][nt] = __builtin_amdgcn_mfma_f32_16x16x32_bf16(a0, b[nt], acc[0][nt], 0, 0, 0);
            acc[1][nt] = __builtin_amdgcn_mfma_f32_16x16x32_bf16(a1, b[nt], acc[1][nt], 0, 0, 0);
        }
        if (ks < 11) { a0 = na0; a1 = na1; }
    }

    if (!FINAL) {
        // D layout: row = quad*4 + r, col = l15 (within each 16x16 tile)
        #pragma unroll
        for (int mt = 0; mt < 2; ++mt) {
            #pragma unroll
            for (int r = 0; r < 4; ++r) {
                int node = rowbase + mt * 16 + quad * 4 + r;
                unsigned short* hp = Hout + (size_t)node * 128 + l15;
                #pragma unroll
                for (int nt = 0; nt < 8; ++nt)
                    hp[nt * 16] = f2b(fmaxf(acc[mt][nt][r], 0.f));
            }
        }
    } else {
        float wc0[8], wc1[8];
        #pragma unroll
        for (int nt = 0; nt < 8; ++nt) {
            wc0[nt] = Wc[(nt * 16 + l15) * 2 + 0];
            wc1[nt] = Wc[(nt * 16 + l15) * 2 + 1];
        }
        float b0 = bc[0], b1 = bc[1];
        #pragma unroll
        for (int mt = 0; mt < 2; ++mt) {
            #pragma unroll
            for (int r = 0; r < 4; ++r) {
                float l0 = 0.f, l1 = 0.f;
                #pragma unroll
                for (int nt = 0; nt < 8; ++nt) {
                    float h = fmaxf(acc[mt][nt][r], 0.f);
                    l0 += h * wc0[nt];
                    l1 += h * wc1[nt];
                }
                #pragma unroll
                for (int off = 8; off > 0; off >>= 1) {
                    l0 += __shfl_down(l0, off, 16);
                    l1 += __shfl_down(l1, off, 16);
                }
                int node = rowbase + mt * 16 + quad * 4 + r;
                if (l15 == 0 && node < N_NODES) {
                    Out[(size_t)node * 2 + 0] = l0 + b0;
                    Out[(size_t)node * 2 + 1] = l1 + b1;
                }
            }
        }
    }
}

extern "C" void kernel_launch(void* const* d_in, const int* in_sizes, int n_in,
                              void* d_out, int out_size, void* d_ws, size_t ws_size,
                              hipStream_t stream)
{
    const float* x      = (const float*)d_in[0];
    const int*   ei     = (const int*)d_in[1];
    const int*   et     = (const int*)d_in[2];
    const float* Wrel1  = (const float*)d_in[3];
    const float* Wroot1 = (const float*)d_in[4];
    const float* b1     = (const float*)d_in[5];
    const float* Wrel2  = (const float*)d_in[6];
    const float* Wroot2 = (const float*)d_in[7];
    const float* b2     = (const float*)d_in[8];
    const float* Wc     = (const float*)d_in[9];
    const float* bc     = (const float*)d_in[10];
    float* out = (float*)d_out;

    char* ws = (char*)d_ws;
    size_t off = 0;
    auto alloc = [&](size_t bytes) {
        void* p = ws + off;
        off += (bytes + 255) & ~(size_t)255;
        return p;
    };
    unsigned short* aggb  = (unsigned short*)alloc((size_t)N_REL * PAD_N * HID * 2);
    unsigned short* xb    = (unsigned short*)alloc((size_t)PAD_N * IN_DIM * 2);
    unsigned short* h1b   = (unsigned short*)alloc((size_t)PAD_N * HID * 2);
    unsigned short* Wp    = (unsigned short*)alloc((size_t)2 * 12 * 8 * 64 * 8 * 2);
    unsigned*       rs    = (unsigned*)alloc((size_t)(M_SEG + 1) * 4);
    unsigned*       cursor= (unsigned*)alloc((size_t)M_SEG * 4);
    unsigned*       bsums = (unsigned*)alloc(256 * 4);
    unsigned*       csr   = (unsigned*)alloc((size_t)N_EDGES * 4);

    const int edge_blocks   = (N_EDGES + 255) / 256;
    const int seg_blocks    = (M_SEG + 255) / 256;
    const int gather_blocks = (M_SEG * 32 + 255) / 256;   // 25000
    const int gemm_blocks   = PAD_N / 128;                // 782
    const int cvt_blocks    = (N_NODES * IN_DIM / 4 + 255) / 256;

    // ---- CSR build + conversions (graph identical for both layers) ----
    hipMemsetAsync(cursor, 0, (size_t)M_SEG * 4, stream);
    hist_kernel<<<edge_blocks, 256, 0, stream>>>(ei, et, cursor);
    scan1_kernel<<<SCAN_NB, 256, 0, stream>>>(cursor, rs, bsums);
    scan2_kernel<<<1, 256, 0, stream>>>(bsums);
    scan3_kernel<<<seg_blocks, 256, 0, stream>>>(rs, bsums, cursor);
    fill_kernel<<<edge_blocks, 256, 0, stream>>>(ei, et, cursor, csr);
    cvt_kernel<<<cvt_blocks, 256, 0, stream>>>(x, xb);
    pack_kernel<<<48, 256, 0, stream>>>(Wroot1, Wrel1, Wroot2, Wrel2, Wp);

    // ---- layer 1 ----
    gather_kernel<<<gather_blocks, 256, 0, stream>>>(xb, rs, csr, aggb);
    gemm_kernel<false><<<gemm_blocks, 256, 0, stream>>>(
        xb, aggb, Wp, b1, h1b, nullptr, nullptr, nullptr);

    // ---- layer 2 ----
    gather_kernel<<<gather_blocks, 256, 0, stream>>>(h1b, rs, csr, aggb);
    gemm_kernel<true><<<gemm_blocks, 256, 0, stream>>>(
        h1b, aggb, Wp + (size_t)12 * 8 * 64 * 8, b2, nullptr, Wc, bc, out);
}

// Round 5
// 286.539 us; speedup vs baseline: 7.4209x; 1.0561x over previous
//
#include <hip/hip_runtime.h>

#define N_NODES 100000
#define PAD_N   100096                   // 782 * 128, padded M for GEMM tiles
#define IN_DIM 128
#define HID 128
#define N_REL 2
#define N_EDGES 500000
#define M_SEG (N_REL * N_NODES)          // 200000 (rel,node) segments
#define SCAN_BLK 1024
#define SCAN_NB ((M_SEG + SCAN_BLK - 1) / SCAN_BLK)   // 196

#define CVT_BLOCKS 12500                 // N_NODES*IN_DIM/4 / 256
#define PACK_BLOCKS 48                   // 2*12*8*64 / 256
#define HIST_BLOCKS 1954                 // ceil(N_EDGES/256)

typedef __attribute__((ext_vector_type(8))) short short8;
typedef __attribute__((ext_vector_type(4))) float float4v;

__device__ __forceinline__ unsigned short f2b(float f) {
    unsigned u = __float_as_uint(f);
    u += 0x7FFFu + ((u >> 16) & 1u);     // round-to-nearest-even
    return (unsigned short)(u >> 16);
}

// ---------------------------------------------------------------------------
// Fused prep: cvt (x fp32->bf16) | pack (weights->B-frag order) | hist.
// Independent jobs split by blockIdx range.
// ---------------------------------------------------------------------------
__global__ __launch_bounds__(256) void prep_kernel(
    const float* __restrict__ X, unsigned short* __restrict__ Xb,
    const float* __restrict__ Wroot1, const float* __restrict__ Wrel1,
    const float* __restrict__ Wroot2, const float* __restrict__ Wrel2,
    unsigned short* __restrict__ Wp,
    const int* __restrict__ ei, const int* __restrict__ et,
    unsigned* __restrict__ cnt)
{
    int bid = blockIdx.x;
    if (bid < CVT_BLOCKS) {
        int i = bid * 256 + threadIdx.x;
        if (i >= N_NODES * IN_DIM / 4) return;
        float4 v = ((const float4*)X)[i];
        ushort4 o;
        o.x = f2b(v.x); o.y = f2b(v.y); o.z = f2b(v.z); o.w = f2b(v.w);
        ((ushort4*)Xb)[i] = o;
    } else if (bid < CVT_BLOCKS + PACK_BLOCKS) {
        int tid = (bid - CVT_BLOCKS) * 256 + threadIdx.x;
        int layer = tid / 6144;
        int rem   = tid % 6144;
        int ks    = rem / 512;
        int rem2  = rem % 512;
        int nt    = rem2 / 64;
        int lane  = rem2 % 64;
        int seg = ks >> 2;
        int kl  = (ks & 3) * 32 + (lane >> 4) * 8;
        int chan = nt * 16 + (lane & 15);
        const float* Wroot = layer ? Wroot2 : Wroot1;
        const float* Wrel  = layer ? Wrel2  : Wrel1;
        const float* W = (seg == 0) ? Wroot : (Wrel + (size_t)(seg - 1) * 128 * 128);
        unsigned short* dst = Wp + (size_t)tid * 8;
        #pragma unroll
        for (int j = 0; j < 8; ++j)
            dst[j] = f2b(W[(size_t)(kl + j) * 128 + chan]);
    } else {
        int e = (bid - CVT_BLOCKS - PACK_BLOCKS) * 256 + threadIdx.x;
        if (e >= N_EDGES) return;
        int dst = ei[N_EDGES + e];
        int r = et[e];
        atomicAdd(cnt + (size_t)r * N_NODES + dst, 1u);
    }
}

// ---------------------------------------------------------------------------
// Scan chain for CSR row starts
// ---------------------------------------------------------------------------
__global__ __launch_bounds__(256) void scan1_kernel(
    const unsigned* __restrict__ cnt,
    unsigned* __restrict__ rs, unsigned* __restrict__ bsums)
{
    __shared__ unsigned sdata[256];
    int t = threadIdx.x;
    int base = blockIdx.x * SCAN_BLK + t * 4;
    unsigned v[4]; unsigned s = 0;
    #pragma unroll
    for (int j = 0; j < 4; ++j) {
        v[j] = (base + j < M_SEG) ? cnt[base + j] : 0u;
        s += v[j];
    }
    sdata[t] = s;
    __syncthreads();
    #pragma unroll
    for (int off = 1; off < 256; off <<= 1) {
        unsigned x = (t >= off) ? sdata[t - off] : 0u;
        __syncthreads();
        if (t >= off) sdata[t] += x;
        __syncthreads();
    }
    unsigned excl = (t > 0) ? sdata[t - 1] : 0u;
    if (t == 255) bsums[blockIdx.x] = sdata[255];
    unsigned run = excl;
    #pragma unroll
    for (int j = 0; j < 4; ++j) {
        if (base + j < M_SEG) rs[base + j] = run;
        run += v[j];
    }
}

__global__ __launch_bounds__(256) void scan2_kernel(unsigned* __restrict__ bsums)
{
    __shared__ unsigned sdata[256];
    int t = threadIdx.x;
    sdata[t] = (t < SCAN_NB) ? bsums[t] : 0u;
    __syncthreads();
    #pragma unroll
    for (int off = 1; off < 256; off <<= 1) {
        unsigned x = (t >= off) ? sdata[t - off] : 0u;
        __syncthreads();
        if (t >= off) sdata[t] += x;
        __syncthreads();
    }
    if (t < SCAN_NB) bsums[t] = (t > 0) ? sdata[t - 1] : 0u;
}

__global__ __launch_bounds__(256) void scan3_kernel(
    unsigned* __restrict__ rs, const unsigned* __restrict__ bsums,
    unsigned* __restrict__ cursor)
{
    int i = blockIdx.x * blockDim.x + threadIdx.x;
    if (i < M_SEG) {
        unsigned v = rs[i] + bsums[i >> 10];
        rs[i] = v;
        cursor[i] = v;
    }
    if (i == 0) rs[M_SEG] = N_EDGES;
}

__global__ __launch_bounds__(256) void fill_kernel(
    const int* __restrict__ ei, const int* __restrict__ et,
    unsigned* __restrict__ cursor, unsigned* __restrict__ csr)
{
    int e = blockIdx.x * blockDim.x + threadIdx.x;
    if (e >= N_EDGES) return;
    int src = ei[e];
    int dst = ei[N_EDGES + e];
    int r = et[e];
    unsigned pos = atomicAdd(cursor + (size_t)r * N_NODES + dst, 1u);
    csr[pos] = (unsigned)src;
}

// ---------------------------------------------------------------------------
// Gather-aggregate (bf16): 32 lanes per (rel,node) segment; writes MEAN row.
// Unrolled by 4 with independent accumulators (avg degree 2.5 -> one batch).
// ---------------------------------------------------------------------------
__global__ __launch_bounds__(256) void gather_kernel(
    const unsigned short* __restrict__ Xb,   // [PAD_N][128] bf16
    const unsigned* __restrict__ rs,
    const unsigned* __restrict__ csr,
    unsigned short* __restrict__ agg)        // [2][PAD_N][128] bf16 means
{
    int t = blockIdx.x * blockDim.x + threadIdx.x;
    int seg = t >> 5;
    int lane = t & 31;
    if (seg >= M_SEG) return;
    unsigned start = rs[seg];
    unsigned end = rs[seg + 1];
    float A0 = 0.f, A1 = 0.f, A2 = 0.f, A3 = 0.f;
    float B0 = 0.f, B1 = 0.f, B2 = 0.f, B3 = 0.f;
    float C0 = 0.f, C1 = 0.f, C2 = 0.f, C3 = 0.f;
    float D0 = 0.f, D1 = 0.f, D2 = 0.f, D3 = 0.f;
    unsigned p = start;
    for (; p + 4 <= end; p += 4) {
        unsigned s0 = csr[p],     s1 = csr[p + 1];
        unsigned s2 = csr[p + 2], s3 = csr[p + 3];
        uint2 v0 = ((const uint2*)(Xb + (size_t)s0 * IN_DIM))[lane];
        uint2 v1 = ((const uint2*)(Xb + (size_t)s1 * IN_DIM))[lane];
        uint2 v2 = ((const uint2*)(Xb + (size_t)s2 * IN_DIM))[lane];
        uint2 v3 = ((const uint2*)(Xb + (size_t)s3 * IN_DIM))[lane];
        A0 += __uint_as_float(v0.x << 16); A1 += __uint_as_float(v0.x & 0xFFFF0000u);
        A2 += __uint_as_float(v0.y << 16); A3 += __uint_as_float(v0.y & 0xFFFF0000u);
        B0 += __uint_as_float(v1.x << 16); B1 += __uint_as_float(v1.x & 0xFFFF0000u);
        B2 += __uint_as_float(v1.y << 16); B3 += __uint_as_float(v1.y & 0xFFFF0000u);
        C0 += __uint_as_float(v2.x << 16); C1 += __uint_as_float(v2.x & 0xFFFF0000u);
        C2 += __uint_as_float(v2.y << 16); C3 += __uint_as_float(v2.y & 0xFFFF0000u);
        D0 += __uint_as_float(v3.x << 16); D1 += __uint_as_float(v3.x & 0xFFFF0000u);
        D2 += __uint_as_float(v3.y << 16); D3 += __uint_as_float(v3.y & 0xFFFF0000u);
    }
    for (; p < end; ++p) {
        unsigned s0 = csr[p];
        uint2 v0 = ((const uint2*)(Xb + (size_t)s0 * IN_DIM))[lane];
        A0 += __uint_as_float(v0.x << 16); A1 += __uint_as_float(v0.x & 0xFFFF0000u);
        A2 += __uint_as_float(v0.y << 16); A3 += __uint_as_float(v0.y & 0xFFFF0000u);
    }
    A0 += B0 + C0 + D0; A1 += B1 + C1 + D1;
    A2 += B2 + C2 + D2; A3 += B3 + C3 + D3;
    unsigned c = end - start;
    float scale = 1.0f / (float)(c > 0u ? c : 1u);
    A0 *= scale; A1 *= scale; A2 *= scale; A3 *= scale;
    int r = seg / N_NODES;
    int n = seg % N_NODES;
    uint2 o;
    o.x = ((unsigned)f2b(A1) << 16) | (unsigned)f2b(A0);
    o.y = ((unsigned)f2b(A3) << 16) | (unsigned)f2b(A2);
    ((uint2*)(agg + ((size_t)r * PAD_N + n) * HID))[lane] = o;
}

// ---------------------------------------------------------------------------
// MFMA GEMM with LDS-staged B.  B-frags are identical for all 4 waves of a
// block, so stage them once per block via global_load_lds (width 16: one 1KB
// frag per instruction, lane-contiguous, wave-uniform LDS base).  Two 48KB
// phases of 6 K-steps.  A-frags: depth-2 register prefetch (full unroll/SSA).
// ---------------------------------------------------------------------------
template <bool FINAL>
__global__ __launch_bounds__(256) void gemm_kernel(
    const unsigned short* __restrict__ Xin,   // [PAD_N][128] bf16
    const unsigned short* __restrict__ agg,   // [2][PAD_N][128] bf16
    const unsigned short* __restrict__ Wp,    // packed [12][8][64][8] bf16
    const float* __restrict__ bias,           // [128] fp32
    unsigned short* __restrict__ Hout,        // [PAD_N][128] bf16 (!FINAL)
    const float* __restrict__ Wc,             // [128][2] fp32 (FINAL)
    const float* __restrict__ bc,             // [2] fp32 (FINAL)
    float* __restrict__ Out)                  // [N][2] fp32 (FINAL)
{
    __shared__ unsigned short ldsB[6 * 8 * 64 * 8];   // 48 KB: 6 K-steps x 8 frags

    const int t    = threadIdx.x;
    const int w    = t >> 6;          // wave 0..3
    const int lane = t & 63;
    const int l15  = lane & 15;
    const int quad = lane >> 4;
    const int rowbase = blockIdx.x * 128 + w * 32;   // this wave's 32 nodes
    const int koff = quad * 8;

    // stage 12 of the 48 frags of phase ph (frags f with f%4 == w)
    auto stage = [&](int ph) {
        #pragma unroll
        for (int fi = 0; fi < 12; ++fi) {
            int f  = fi * 4 + w;          // 0..47
            int sl = f >> 3;              // phase-local K-step
            int nt = f & 7;
            int ks = ph * 6 + sl;
            const unsigned short* g = Wp + ((size_t)(ks * 8 + nt) * 64 + lane) * 8;
            unsigned short* l = ldsB + (size_t)(sl * 8 + nt) * 512;   // wave-uniform
            __builtin_amdgcn_global_load_lds(
                (const __attribute__((address_space(1))) unsigned int*)g,
                (__attribute__((address_space(3))) unsigned int*)l, 16, 0, 0);
        }
    };

    // A-frag base pointers (constant over ks)
    const unsigned short* aS0m0 = Xin + (size_t)(rowbase + l15) * 128 + koff;
    const unsigned short* aS0m1 = aS0m0 + 16 * 128;
    const unsigned short* aS1m0 = agg + (size_t)(rowbase + l15) * 128 + koff;
    const unsigned short* aS1m1 = aS1m0 + 16 * 128;
    const unsigned short* aS2m0 = aS1m0 + (size_t)PAD_N * 128;
    const unsigned short* aS2m1 = aS2m0 + 16 * 128;

    auto aload = [&](int ks, int mt) -> short8 {
        int seg = ks >> 2;
        int kc  = (ks & 3) * 32;
        const unsigned short* p =
            (seg == 0) ? (mt ? aS0m1 : aS0m0) :
            (seg == 1) ? (mt ? aS1m1 : aS1m0) :
                         (mt ? aS2m1 : aS2m0);
        return *(const short8*)(p + kc);
    };

    float4v acc[2][8];
    #pragma unroll
    for (int nt = 0; nt < 8; ++nt) {
        float bv = bias[nt * 16 + l15];
        #pragma unroll
        for (int mt = 0; mt < 2; ++mt)
            acc[mt][nt] = float4v{bv, bv, bv, bv};
    }

    short8 a0[12], a1[12];
    stage(0);
    a0[0] = aload(0, 0); a1[0] = aload(0, 1);
    a0[1] = aload(1, 0); a1[1] = aload(1, 1);
    __syncthreads();                      // phase-0 B staged (vmcnt drained)

    #pragma unroll
    for (int sl = 0; sl < 6; ++sl) {
        int ks = sl;
        if (ks + 2 < 12) { a0[ks + 2] = aload(ks + 2, 0); a1[ks + 2] = aload(ks + 2, 1); }
        short8 b[8];
        #pragma unroll
        for (int nt = 0; nt < 8; ++nt)
            b[nt] = *(const short8*)(ldsB + (size_t)(sl * 8 + nt) * 512 + lane * 8);
        #pragma unroll
        for (int nt = 0; nt < 8; ++nt) {
            acc[0][nt] = __builtin_amdgcn_mfma_f32_16x16x32_bf16(a0[ks], b[nt], acc[0][nt], 0, 0, 0);
            acc[1][nt] = __builtin_amdgcn_mfma_f32_16x16x32_bf16(a1[ks], b[nt], acc[1][nt], 0, 0, 0);
        }
    }

    __syncthreads();                      // all waves done reading phase-0 LDS
    stage(1);
    __syncthreads();                      // phase-1 B staged

    #pragma unroll
    for (int sl = 0; sl < 6; ++sl) {
        int ks = 6 + sl;
        if (ks + 2 < 12) { a0[ks + 2] = aload(ks + 2, 0); a1[ks + 2] = aload(ks + 2, 1); }
        short8 b[8];
        #pragma unroll
        for (int nt = 0; nt < 8; ++nt)
            b[nt] = *(const short8*)(ldsB + (size_t)(sl * 8 + nt) * 512 + lane * 8);
        #pragma unroll
        for (int nt = 0; nt < 8; ++nt) {
            acc[0][nt] = __builtin_amdgcn_mfma_f32_16x16x32_bf16(a0[ks], b[nt], acc[0][nt], 0, 0, 0);
            acc[1][nt] = __builtin_amdgcn_mfma_f32_16x16x32_bf16(a1[ks], b[nt], acc[1][nt], 0, 0, 0);
        }
    }

    if (!FINAL) {
        // D layout: row = quad*4 + r, col = l15 (within each 16x16 tile)
        #pragma unroll
        for (int mt = 0; mt < 2; ++mt) {
            #pragma unroll
            for (int r = 0; r < 4; ++r) {
                int node = rowbase + mt * 16 + quad * 4 + r;
                unsigned short* hp = Hout + (size_t)node * 128 + l15;
                #pragma unroll
                for (int nt = 0; nt < 8; ++nt)
                    hp[nt * 16] = f2b(fmaxf(acc[mt][nt][r], 0.f));
            }
        }
    } else {
        float wc0[8], wc1[8];
        #pragma unroll
        for (int nt = 0; nt < 8; ++nt) {
            wc0[nt] = Wc[(nt * 16 + l15) * 2 + 0];
            wc1[nt] = Wc[(nt * 16 + l15) * 2 + 1];
        }
        float b0 = bc[0], b1 = bc[1];
        #pragma unroll
        for (int mt = 0; mt < 2; ++mt) {
            #pragma unroll
            for (int r = 0; r < 4; ++r) {
                float l0 = 0.f, l1 = 0.f;
                #pragma unroll
                for (int nt = 0; nt < 8; ++nt) {
                    float h = fmaxf(acc[mt][nt][r], 0.f);
                    l0 += h * wc0[nt];
                    l1 += h * wc1[nt];
                }
                #pragma unroll
                for (int off = 8; off > 0; off >>= 1) {
                    l0 += __shfl_down(l0, off, 16);
                    l1 += __shfl_down(l1, off, 16);
                }
                int node = rowbase + mt * 16 + quad * 4 + r;
                if (l15 == 0 && node < N_NODES) {
                    Out[(size_t)node * 2 + 0] = l0 + b0;
                    Out[(size_t)node * 2 + 1] = l1 + b1;
                }
            }
        }
    }
}

extern "C" void kernel_launch(void* const* d_in, const int* in_sizes, int n_in,
                              void* d_out, int out_size, void* d_ws, size_t ws_size,
                              hipStream_t stream)
{
    const float* x      = (const float*)d_in[0];
    const int*   ei     = (const int*)d_in[1];
    const int*   et     = (const int*)d_in[2];
    const float* Wrel1  = (const float*)d_in[3];
    const float* Wroot1 = (const float*)d_in[4];
    const float* b1     = (const float*)d_in[5];
    const float* Wrel2  = (const float*)d_in[6];
    const float* Wroot2 = (const float*)d_in[7];
    const float* b2     = (const float*)d_in[8];
    const float* Wc     = (const float*)d_in[9];
    const float* bc     = (const float*)d_in[10];
    float* out = (float*)d_out;

    char* ws = (char*)d_ws;
    size_t off = 0;
    auto alloc = [&](size_t bytes) {
        void* p = ws + off;
        off += (bytes + 255) & ~(size_t)255;
        return p;
    };
    unsigned short* aggb  = (unsigned short*)alloc((size_t)N_REL * PAD_N * HID * 2);
    unsigned short* xb    = (unsigned short*)alloc((size_t)PAD_N * IN_DIM * 2);
    unsigned short* h1b   = (unsigned short*)alloc((size_t)PAD_N * HID * 2);
    unsigned short* Wp    = (unsigned short*)alloc((size_t)2 * 12 * 8 * 64 * 8 * 2);
    unsigned*       rs    = (unsigned*)alloc((size_t)(M_SEG + 1) * 4);
    unsigned*       cursor= (unsigned*)alloc((size_t)M_SEG * 4);
    unsigned*       bsums = (unsigned*)alloc(256 * 4);
    unsigned*       csr   = (unsigned*)alloc((size_t)N_EDGES * 4);

    const int edge_blocks   = (N_EDGES + 255) / 256;
    const int seg_blocks    = (M_SEG + 255) / 256;
    const int gather_blocks = (M_SEG * 32 + 255) / 256;   // 25000
    const int gemm_blocks   = PAD_N / 128;                // 782
    const int prep_blocks   = CVT_BLOCKS + PACK_BLOCKS + HIST_BLOCKS;

    // ---- CSR build + conversions (graph identical for both layers) ----
    hipMemsetAsync(cursor, 0, (size_t)M_SEG * 4, stream);
    prep_kernel<<<prep_blocks, 256, 0, stream>>>(
        x, xb, Wroot1, Wrel1, Wroot2, Wrel2, Wp, ei, et, cursor);
    scan1_kernel<<<SCAN_NB, 256, 0, stream>>>(cursor, rs, bsums);
    scan2_kernel<<<1, 256, 0, stream>>>(bsums);
    scan3_kernel<<<seg_blocks, 256, 0, stream>>>(rs, bsums, cursor);
    fill_kernel<<<edge_blocks, 256, 0, stream>>>(ei, et, cursor, csr);

    // ---- layer 1 ----
    gather_kernel<<<gather_blocks, 256, 0, stream>>>(xb, rs, csr, aggb);
    gemm_kernel<false><<<gemm_blocks, 256, 0, stream>>>(
        xb, aggb, Wp, b1, h1b, nullptr, nullptr, nullptr);

    // ---- layer 2 ----
    gather_kernel<<<gather_blocks, 256, 0, stream>>>(h1b, rs, csr, aggb);
    gemm_kernel<true><<<gemm_blocks, 256, 0, stream>>>(
        h1b, aggb, Wp + (size_t)12 * 8 * 64 * 8, b2, nullptr, Wc, bc, out);
}